// Round 2
// baseline (343.520 us; speedup 1.0000x reference)
//
#include <hip/hip_runtime.h>
#include <hip/hip_bf16.h>

// Problem constants: B=16, T=512, H=1024, L=8192, D=256
// logits[b,l] = sum_t softmax_t(Q[l]·K[b,t]/16) * (Wout[l]·V[b,t]) + bias[l]

typedef __bf16 bf16x8 __attribute__((ext_vector_type(8)));
typedef float f32x4 __attribute__((ext_vector_type(4)));

__device__ __forceinline__ unsigned short f2bf(float f) {
    // round-to-nearest-even fp32 -> bf16 (finite inputs only)
    unsigned int u = __builtin_bit_cast(unsigned int, f);
    unsigned int lsb = (u >> 16) & 1u;
    u += 0x7fffu + lsb;
    return (unsigned short)(u >> 16);
}

// -----------------------------------------------------------------------------
// Fused fp32->bf16 conversion for all five tensors in one launch.
// ws segment order (Xb,Qb,Wob,Wk|Wv) matches input order, so the dst ushort4
// index equals the global float4 index.
// Segments (float4 units): X 2097152 | Q 524288 | Wo 524288 | Wk 65536 | Wv 65536
// -----------------------------------------------------------------------------
__global__ __launch_bounds__(256) void cvt_all(const float* __restrict__ X,
                                               const float* __restrict__ Q,
                                               const float* __restrict__ Wo,
                                               const float* __restrict__ Wk,
                                               const float* __restrict__ Wv,
                                               unsigned short* __restrict__ dst) {
    int base = blockIdx.x * 1024 + threadIdx.x;
#pragma unroll
    for (int r = 0; r < 4; ++r) {
        int idx = base + r * 256;  // float4 index, < 3276800
        const float* src;
        int off;
        if (idx < 2097152)      { src = X;  off = idx; }
        else if (idx < 2621440) { src = Q;  off = idx - 2097152; }
        else if (idx < 3145728) { src = Wo; off = idx - 2621440; }
        else if (idx < 3211264) { src = Wk; off = idx - 3145728; }
        else                    { src = Wv; off = idx - 3211264; }
        float4 v = ((const float4*)src)[off];
        ushort4 o;
        o.x = f2bf(v.x); o.y = f2bf(v.y); o.z = f2bf(v.z); o.w = f2bf(v.w);
        ((ushort4*)dst)[idx] = o;
    }
}

// -----------------------------------------------------------------------------
// Phase 1: K,V projection. C[m][n] = sum_h X[m][h] * Wkv[n][h]
//   M = B*T = 8192, N = 512 (n<256 -> K dim d=n; else V dim d=n-256), K = 1024
// Tile: 128m x 128n per block (grid 64x4), 4 waves in 2x2, wave = 64m x 64n.
// -----------------------------------------------------------------------------
__global__ __launch_bounds__(256) void kv_gemm(const unsigned short* __restrict__ Xb,
                                               const unsigned short* __restrict__ Wb,
                                               unsigned short* __restrict__ Kb,
                                               unsigned short* __restrict__ Vb) {
    __shared__ unsigned short Xs[128 * 72];  // 64-wide h-chunk, stride 72 (pad 8)
    __shared__ unsigned short Ws[128 * 72];
    const int bid = blockIdx.x;
    const int nt = bid & 3, mt = bid >> 2;
    const int m0 = mt * 128, n0 = nt * 128;
    const int tid = threadIdx.x;
    const int lane = tid & 63, w = tid >> 6;
    const int q = lane >> 4, ln = lane & 15;
    const int wm = (w & 1) * 64, wn = (w >> 1) * 64;

    f32x4 acc[4][4];
#pragma unroll
    for (int mi = 0; mi < 4; ++mi)
#pragma unroll
        for (int ni = 0; ni < 4; ++ni) acc[mi][ni] = f32x4{0.f, 0.f, 0.f, 0.f};

#pragma unroll 1
    for (int h0 = 0; h0 < 1024; h0 += 64) {
#pragma unroll
        for (int i = 0; i < 4; ++i) {  // stage X and Wkv tiles: 128 rows x 64 h each
            int c = tid + i * 256;
            int row = c >> 3, off = (c & 7) << 3;
            *(uint4*)(&Xs[row * 72 + off]) = *(const uint4*)(&Xb[(m0 + row) * 1024 + h0 + off]);
            *(uint4*)(&Ws[row * 72 + off]) = *(const uint4*)(&Wb[(n0 + row) * 1024 + h0 + off]);
        }
        __syncthreads();
#pragma unroll
        for (int ks = 0; ks < 64; ks += 32) {
            bf16x8 a[4], b[4];
#pragma unroll
            for (int mi = 0; mi < 4; ++mi)
                a[mi] = *(const bf16x8*)(&Xs[(wm + mi * 16 + ln) * 72 + ks + q * 8]);
#pragma unroll
            for (int ni = 0; ni < 4; ++ni)
                b[ni] = *(const bf16x8*)(&Ws[(wn + ni * 16 + ln) * 72 + ks + q * 8]);
#pragma unroll
            for (int mi = 0; mi < 4; ++mi)
#pragma unroll
                for (int ni = 0; ni < 4; ++ni)
                    acc[mi][ni] = __builtin_amdgcn_mfma_f32_16x16x32_bf16(
                        a[mi], b[ni], acc[mi][ni], 0, 0, 0);
        }
        __syncthreads();
    }
    // epilogue: C/D layout col(=n) = ln, row(=m) = q*4+reg
    {
        unsigned short* dst = (n0 < 256) ? Kb : Vb;  // uniform per block
        const int d0 = (n0 & 255) + wn;
#pragma unroll
        for (int mi = 0; mi < 4; ++mi)
#pragma unroll
            for (int ni = 0; ni < 4; ++ni) {
                int d = d0 + ni * 16 + ln;
#pragma unroll
                for (int r = 0; r < 4; ++r) {
                    int m = m0 + wm + mi * 16 + q * 4 + r;
                    dst[m * 256 + d] = f2bf(acc[mi][ni][r]);
                }
            }
    }
}

// -----------------------------------------------------------------------------
// Phase 2: fused S = Q·K^T, P = Wout·V^T, softmax-weighted reduce over t.
// Grid: 16 b x 64 l-tiles (128 l each), 4 waves, wave = 32l x 64t.
// A-operands (Q, Wout fragments for ALL of d=256) live in registers for the
// whole kernel: 32 x bf16x8 = 128 VGPRs. LDS holds only K/V t-chunks
// (64t x 128d, stride 136), so the hot loop reads B-fragments only.
// __launch_bounds__(256,2): 2 waves/EU -> 256-VGPR budget, 2 blocks/CU.
// -----------------------------------------------------------------------------
__global__ __launch_bounds__(256, 2) void attn_fused(const unsigned short* __restrict__ Qb,
                                                     const unsigned short* __restrict__ Wob,
                                                     const unsigned short* __restrict__ Kb,
                                                     const unsigned short* __restrict__ Vb,
                                                     const int* __restrict__ mask,
                                                     const float* __restrict__ bias,
                                                     float* __restrict__ out) {
    __shared__ unsigned short Ks[64 * 136];  // 64t x 128d, stride 136 (pad 8)
    __shared__ unsigned short Vs[64 * 136];
    const int bid = blockIdx.x;
    const int bb = bid >> 6;             // batch
    const int l0 = (bid & 63) * 128;     // l-tile origin
    const int tid = threadIdx.x;
    const int lane = tid & 63, w = tid >> 6;
    const int q = lane >> 4, ln = lane & 15;

    // Prologue: A-fragments for the full d=256 (8 k-steps of 32), in registers.
    // Fragment kk: lane holds row (l0+w*32+mi*16+ln), cols kk*32+q*8 .. +8.
    bf16x8 aQ[2][8], aW[2][8];
#pragma unroll
    for (int mi = 0; mi < 2; ++mi) {
        const int row = (l0 + w * 32 + mi * 16 + ln) * 256;
#pragma unroll
        for (int kk = 0; kk < 8; ++kk) {
            aQ[mi][kk] = *(const bf16x8*)(&Qb[row + kk * 32 + q * 8]);
            aW[mi][kk] = *(const bf16x8*)(&Wob[row + kk * 32 + q * 8]);
        }
    }

    float num[2][4], den[2][4];
#pragma unroll
    for (int mi = 0; mi < 2; ++mi)
#pragma unroll
        for (int r = 0; r < 4; ++r) { num[mi][r] = 0.f; den[mi][r] = 0.f; }

#pragma unroll 1
    for (int t0 = 0; t0 < 512; t0 += 64) {
        f32x4 Sa[2][4], Pa[2][4];
#pragma unroll
        for (int mi = 0; mi < 2; ++mi)
#pragma unroll
            for (int ni = 0; ni < 4; ++ni) {
                Sa[mi][ni] = f32x4{0.f, 0.f, 0.f, 0.f};
                Pa[mi][ni] = f32x4{0.f, 0.f, 0.f, 0.f};
            }

#pragma unroll 1
        for (int dh = 0; dh < 2; ++dh) {  // two 128-d halves
#pragma unroll
            for (int i = 0; i < 4; ++i) {  // stage K,V chunk: 64t x 128d each
                int c = tid + i * 256;          // < 1024
                int row = c >> 4, col = (c & 15) << 3;
                int src = (bb * 512 + t0 + row) * 256 + dh * 128 + col;
                *(uint4*)(&Ks[row * 136 + col]) = *(const uint4*)(&Kb[src]);
                *(uint4*)(&Vs[row * 136 + col]) = *(const uint4*)(&Vb[src]);
            }
            __syncthreads();
#pragma unroll
            for (int kstep = 0; kstep < 4; ++kstep) {
                const int kk = dh * 4 + kstep;
                bf16x8 bK[4], bV[4];
#pragma unroll
                for (int ni = 0; ni < 4; ++ni) {
                    int ro = (ni * 16 + ln) * 136 + kstep * 32 + q * 8;
                    bK[ni] = *(const bf16x8*)(&Ks[ro]);
                    bV[ni] = *(const bf16x8*)(&Vs[ro]);
                }
#pragma unroll
                for (int mi = 0; mi < 2; ++mi)
#pragma unroll
                    for (int ni = 0; ni < 4; ++ni) {
                        Sa[mi][ni] = __builtin_amdgcn_mfma_f32_16x16x32_bf16(
                            aQ[mi][kk], bK[ni], Sa[mi][ni], 0, 0, 0);
                        Pa[mi][ni] = __builtin_amdgcn_mfma_f32_16x16x32_bf16(
                            aW[mi][kk], bV[ni], Pa[mi][ni], 0, 0, 0);
                    }
            }
            __syncthreads();
        }
        // softmax partial accumulation. D layout: col(=t) = ln, row(=l) = q*4+r.
        // S values ~N(0,0.02): exp without max-subtraction is exact softmax.
#pragma unroll
        for (int ni = 0; ni < 4; ++ni) {
            int t = t0 + ni * 16 + ln;
            bool m_ok = mask[bb * 512 + t] != 0;
#pragma unroll
            for (int mi = 0; mi < 2; ++mi)
#pragma unroll
                for (int r = 0; r < 4; ++r) {
                    float e = m_ok ? __expf(Sa[mi][ni][r] * 0.0625f) : 0.0f;
                    den[mi][r] += e;
                    num[mi][r] += e * Pa[mi][ni][r];
                }
        }
    }
    // reduce num/den over the 16 lanes (= 16 t-columns) of each quad group
#pragma unroll
    for (int mi = 0; mi < 2; ++mi)
#pragma unroll
        for (int r = 0; r < 4; ++r) {
            float n_ = num[mi][r], d_ = den[mi][r];
#pragma unroll
            for (int o = 1; o < 16; o <<= 1) {
                n_ += __shfl_xor(n_, o);
                d_ += __shfl_xor(d_, o);
            }
            if (ln == 0) {
                int l = l0 + w * 32 + mi * 16 + q * 4 + r;
                out[bb * 8192 + l] = n_ / d_ + bias[l];
            }
        }
}

extern "C" void kernel_launch(void* const* d_in, const int* in_sizes, int n_in,
                              void* d_out, int out_size, void* d_ws, size_t ws_size,
                              hipStream_t stream) {
    const float* X    = (const float*)d_in[0];  // [16,512,1024]
    const int*   mask = (const int*)d_in[1];    // [16,512]
    const float* Q    = (const float*)d_in[2];  // [8192,256]
    const float* Wk   = (const float*)d_in[3];  // [256,1024]
    const float* Wv   = (const float*)d_in[4];  // [256,1024]
    const float* Wo   = (const float*)d_in[5];  // [8192,256]
    const float* bias = (const float*)d_in[6];  // [8192]
    float* out = (float*)d_out;                 // [16,8192]

    unsigned short* Xb   = (unsigned short*)d_ws;          // 8,388,608 elems
    unsigned short* Qb   = Xb + 8388608ull;                // 2,097,152
    unsigned short* Wob  = Qb + 2097152ull;                // 2,097,152
    unsigned short* Wkvb = Wob + 2097152ull;               // 524,288 (Wk 0-255, Wv 256-511)
    unsigned short* Kb   = Wkvb + 524288ull;               // 2,097,152
    unsigned short* Vb   = Kb + 2097152ull;                // 2,097,152  (total ~34.6 MB)

    cvt_all<<<dim3(3200), 256, 0, stream>>>(X, Q, Wo, Wk, Wv, Xb);
    kv_gemm<<<dim3(256), 256, 0, stream>>>(Xb, Wkvb, Kb, Vb);
    attn_fused<<<dim3(1024), 256, 0, stream>>>(Qb, Wob, Kb, Vb, mask, bias, out);
}

// Round 3
// 235.009 us; speedup vs baseline: 1.4617x; 1.4617x over previous
//
#include <hip/hip_runtime.h>
#include <hip/hip_bf16.h>

// Problem constants: B=16, T=512, H=1024, L=8192, D=256
// logits[b,l] = sum_t softmax_t(Q[l]·K[b,t]/16) * (Wout[l]·V[b,t]) + bias[l]

typedef __bf16 bf16x8 __attribute__((ext_vector_type(8)));
typedef float f32x4 __attribute__((ext_vector_type(4)));

__device__ __forceinline__ unsigned short f2bf(float f) {
    // round-to-nearest-even fp32 -> bf16 (finite inputs only)
    unsigned int u = __builtin_bit_cast(unsigned int, f);
    unsigned int lsb = (u >> 16) & 1u;
    u += 0x7fffu + lsb;
    return (unsigned short)(u >> 16);
}

// async global->LDS DMA: each lane contributes 16 B; LDS dest = wave-uniform
// base + lane*16 (m104/m108). Dest must be contiguous per 1024-B group.
__device__ __forceinline__ void gld_lds16(const void* g, void* l) {
    __builtin_amdgcn_global_load_lds((__attribute__((address_space(1))) void*)g,
                                     (__attribute__((address_space(3))) void*)l,
                                     16, 0, 0);
}

// -----------------------------------------------------------------------------
// Fused fp32->bf16 conversion for all five tensors in one launch.
// Segments (float4 units): X 2097152 | Q 524288 | Wo 524288 | Wk 65536 | Wv 65536
// -----------------------------------------------------------------------------
__global__ __launch_bounds__(256) void cvt_all(const float* __restrict__ X,
                                               const float* __restrict__ Q,
                                               const float* __restrict__ Wo,
                                               const float* __restrict__ Wk,
                                               const float* __restrict__ Wv,
                                               unsigned short* __restrict__ dst) {
    int base = blockIdx.x * 1024 + threadIdx.x;
#pragma unroll
    for (int r = 0; r < 4; ++r) {
        int idx = base + r * 256;  // float4 index, < 3276800
        const float* src;
        int off;
        if (idx < 2097152)      { src = X;  off = idx; }
        else if (idx < 2621440) { src = Q;  off = idx - 2097152; }
        else if (idx < 3145728) { src = Wo; off = idx - 2621440; }
        else if (idx < 3211264) { src = Wk; off = idx - 3145728; }
        else                    { src = Wv; off = idx - 3211264; }
        float4 v = ((const float4*)src)[off];
        ushort4 o;
        o.x = f2bf(v.x); o.y = f2bf(v.y); o.z = f2bf(v.z); o.w = f2bf(v.w);
        ((ushort4*)dst)[idx] = o;
    }
}

// -----------------------------------------------------------------------------
// Phase 1: K,V projection. C[m][n] = sum_h X[m][h] * Wkv[n][h]
//   M = B*T = 8192, N = 512 (n<256 -> K dim d=n; else V dim d=n-256), K = 1024
// Tile: 128m x 128n per block (grid 64x4), 4 waves in 2x2, wave = 64m x 64n.
// -----------------------------------------------------------------------------
__global__ __launch_bounds__(256) void kv_gemm(const unsigned short* __restrict__ Xb,
                                               const unsigned short* __restrict__ Wb,
                                               unsigned short* __restrict__ Kb,
                                               unsigned short* __restrict__ Vb) {
    __shared__ unsigned short Xs[128 * 72];  // 64-wide h-chunk, stride 72 (pad 8)
    __shared__ unsigned short Ws[128 * 72];
    const int bid = blockIdx.x;
    const int nt = bid & 3, mt = bid >> 2;
    const int m0 = mt * 128, n0 = nt * 128;
    const int tid = threadIdx.x;
    const int lane = tid & 63, w = tid >> 6;
    const int q = lane >> 4, ln = lane & 15;
    const int wm = (w & 1) * 64, wn = (w >> 1) * 64;

    f32x4 acc[4][4];
#pragma unroll
    for (int mi = 0; mi < 4; ++mi)
#pragma unroll
        for (int ni = 0; ni < 4; ++ni) acc[mi][ni] = f32x4{0.f, 0.f, 0.f, 0.f};

#pragma unroll 1
    for (int h0 = 0; h0 < 1024; h0 += 64) {
#pragma unroll
        for (int i = 0; i < 4; ++i) {  // stage X and Wkv tiles: 128 rows x 64 h each
            int c = tid + i * 256;
            int row = c >> 3, off = (c & 7) << 3;
            *(uint4*)(&Xs[row * 72 + off]) = *(const uint4*)(&Xb[(m0 + row) * 1024 + h0 + off]);
            *(uint4*)(&Ws[row * 72 + off]) = *(const uint4*)(&Wb[(n0 + row) * 1024 + h0 + off]);
        }
        __syncthreads();
#pragma unroll
        for (int ks = 0; ks < 64; ks += 32) {
            bf16x8 a[4], b[4];
#pragma unroll
            for (int mi = 0; mi < 4; ++mi)
                a[mi] = *(const bf16x8*)(&Xs[(wm + mi * 16 + ln) * 72 + ks + q * 8]);
#pragma unroll
            for (int ni = 0; ni < 4; ++ni)
                b[ni] = *(const bf16x8*)(&Ws[(wn + ni * 16 + ln) * 72 + ks + q * 8]);
#pragma unroll
            for (int mi = 0; mi < 4; ++mi)
#pragma unroll
                for (int ni = 0; ni < 4; ++ni)
                    acc[mi][ni] = __builtin_amdgcn_mfma_f32_16x16x32_bf16(
                        a[mi], b[ni], acc[mi][ni], 0, 0, 0);
        }
        __syncthreads();
    }
    // epilogue: C/D layout col(=n) = ln, row(=m) = q*4+reg
    {
        unsigned short* dst = (n0 < 256) ? Kb : Vb;  // uniform per block
        const int d0 = (n0 & 255) + wn;
#pragma unroll
        for (int mi = 0; mi < 4; ++mi)
#pragma unroll
            for (int ni = 0; ni < 4; ++ni) {
                int d = d0 + ni * 16 + ln;
#pragma unroll
                for (int r = 0; r < 4; ++r) {
                    int m = m0 + wm + mi * 16 + q * 4 + r;
                    dst[m * 256 + d] = f2bf(acc[mi][ni][r]);
                }
            }
    }
}

// -----------------------------------------------------------------------------
// Phase 2: fused S = Q·K^T, P = Wout·V^T, softmax-weighted reduce over t.
// Grid: 16 b x 64 l-tiles. Block = 512 threads = 8 waves in a 4l x 2t grid;
// block tile 128l x 64t per t-chunk, wave tile 32l x 32t.
// A-operands (Q,Wout, full d=256) live in registers: 32 x bf16x8 = 128 VGPRs,
// ALL indices compile-time (the round-2 spill was dynamic aQ[mi][dh*4+k]).
// K/V staged by global_load_lds DMA into double-buffered LDS; layout = groups
// of 2 rows (1024 B data + 16 B pad) so the DMA dest is contiguous per group
// while fragment reads stay at free 2-way bank aliasing.
// -----------------------------------------------------------------------------
__global__ __launch_bounds__(512, 2) void attn_fused(const unsigned short* __restrict__ Qb,
                                                     const unsigned short* __restrict__ Wob,
                                                     const unsigned short* __restrict__ Kb,
                                                     const unsigned short* __restrict__ Vb,
                                                     const int* __restrict__ mask,
                                                     const float* __restrict__ bias,
                                                     float* __restrict__ out) {
    // 32 groups x 520 ushorts (1040 B: rows 2g,2g+1 + 16 B pad) per buffer
    __shared__ unsigned short Ks[2][16640];
    __shared__ unsigned short Vs[2][16640];
    const int bid = blockIdx.x;
    const int bb = bid >> 6;             // batch
    const int l0 = (bid & 63) * 128;     // l-tile origin
    const int tid = threadIdx.x;
    const int lane = tid & 63, w = tid >> 6;
    const int wl = w & 3, wt = w >> 2;   // wave grid 4l x 2t
    const int q = lane >> 4, ln = lane & 15;

    // Prologue: A-fragments for full d=256 (8 k-steps of 32) in registers.
    bf16x8 aQ[2][8], aW[2][8];
#pragma unroll
    for (int mi = 0; mi < 2; ++mi) {
        const int row = (l0 + wl * 32 + mi * 16 + ln) * 256;
#pragma unroll
        for (int kk = 0; kk < 8; ++kk) {
            aQ[mi][kk] = *(const bf16x8*)(&Qb[row + kk * 32 + q * 8]);
            aW[mi][kk] = *(const bf16x8*)(&Wob[row + kk * 32 + q * 8]);
        }
    }

    float num[2][4], den[2][4];
#pragma unroll
    for (int mi = 0; mi < 2; ++mi)
#pragma unroll
        for (int r = 0; r < 4; ++r) { num[mi][r] = 0.f; den[mi][r] = 0.f; }

    // DMA-stage chunk c (64t x 256d of K and V) into buffer parity c&1.
    // 64 groups of 1024 B (K: gid 0..31, V: 32..63); each wave issues 8.
    auto stage = [&](int c) {
        const int p = c & 1;
        const int t0 = c * 64;
#pragma unroll
        for (int j = 0; j < 8; ++j) {
            int gid = w * 8 + j;        // wave-uniform
            int g = gid & 31;
            const unsigned short* srcb = (gid < 32) ? Kb : Vb;
            const unsigned short* src =
                srcb + (((size_t)(bb * 512 + t0 + 2 * g)) << 8) + lane * 8;
            unsigned short* dstb = (gid < 32) ? &Ks[p][0] : &Vs[p][0];
            gld_lds16(src, dstb + g * 520);
        }
    };
    stage(0);

#pragma unroll 1
    for (int c = 0; c < 8; ++c) {
        __syncthreads();          // drains this wave's DMAs -> chunk c ready
        if (c < 7) stage(c + 1);  // prefetch lands during compute below
        const int p = c & 1;

        f32x4 Sa[2][2], Pa[2][2];
#pragma unroll
        for (int mi = 0; mi < 2; ++mi)
#pragma unroll
            for (int ni = 0; ni < 2; ++ni) {
                Sa[mi][ni] = f32x4{0.f, 0.f, 0.f, 0.f};
                Pa[mi][ni] = f32x4{0.f, 0.f, 0.f, 0.f};
            }

#pragma unroll
        for (int kk = 0; kk < 8; ++kk) {
            bf16x8 bK[2], bV[2];
#pragma unroll
            for (int ni = 0; ni < 2; ++ni) {
                int rr = wt * 32 + ni * 16 + ln;
                int off = (rr >> 1) * 520 + (rr & 1) * 256 + kk * 32 + q * 8;
                bK[ni] = *(const bf16x8*)(&Ks[p][off]);
                bV[ni] = *(const bf16x8*)(&Vs[p][off]);
            }
#pragma unroll
            for (int mi = 0; mi < 2; ++mi)
#pragma unroll
                for (int ni = 0; ni < 2; ++ni) {
                    Sa[mi][ni] = __builtin_amdgcn_mfma_f32_16x16x32_bf16(
                        aQ[mi][kk], bK[ni], Sa[mi][ni], 0, 0, 0);
                    Pa[mi][ni] = __builtin_amdgcn_mfma_f32_16x16x32_bf16(
                        aW[mi][kk], bV[ni], Pa[mi][ni], 0, 0, 0);
                }
        }
        // softmax partials. D layout: col(=t) = ln, row(=l) = q*4+r.
        // S ~N(0,0.02): exp without max-subtraction is exact softmax.
        const int t0 = c * 64;
#pragma unroll
        for (int ni = 0; ni < 2; ++ni) {
            int t = t0 + wt * 32 + ni * 16 + ln;
            bool ok = mask[bb * 512 + t] != 0;
#pragma unroll
            for (int mi = 0; mi < 2; ++mi)
#pragma unroll
                for (int r = 0; r < 4; ++r) {
                    float e = ok ? __expf(Sa[mi][ni][r] * 0.0625f) : 0.0f;
                    den[mi][r] += e;
                    num[mi][r] += e * Pa[mi][ni][r];
                }
        }
    }

    // reduce over the 16 t-columns (lanes ln) of each quad group
#pragma unroll
    for (int mi = 0; mi < 2; ++mi)
#pragma unroll
        for (int r = 0; r < 4; ++r) {
#pragma unroll
            for (int o = 1; o < 16; o <<= 1) {
                num[mi][r] += __shfl_xor(num[mi][r], o);
                den[mi][r] += __shfl_xor(den[mi][r], o);
            }
        }

    // combine the two t-wave-columns (wt=0,1) via LDS (buffers now dead)
    __syncthreads();
    float* red = (float*)&Ks[0][0];
    if (wt == 1 && ln == 0) {
#pragma unroll
        for (int mi = 0; mi < 2; ++mi)
#pragma unroll
            for (int r = 0; r < 4; ++r) {
                int idx = ((wl * 2 + mi) * 4 + q) * 4 + r;
                red[idx] = num[mi][r];
                red[128 + idx] = den[mi][r];
            }
    }
    __syncthreads();
    if (wt == 0 && ln == 0) {
#pragma unroll
        for (int mi = 0; mi < 2; ++mi)
#pragma unroll
            for (int r = 0; r < 4; ++r) {
                int idx = ((wl * 2 + mi) * 4 + q) * 4 + r;
                float nt = num[mi][r] + red[idx];
                float dt = den[mi][r] + red[128 + idx];
                int l = l0 + wl * 32 + mi * 16 + q * 4 + r;
                out[bb * 8192 + l] = nt / dt + bias[l];
            }
    }
}

extern "C" void kernel_launch(void* const* d_in, const int* in_sizes, int n_in,
                              void* d_out, int out_size, void* d_ws, size_t ws_size,
                              hipStream_t stream) {
    const float* X    = (const float*)d_in[0];  // [16,512,1024]
    const int*   mask = (const int*)d_in[1];    // [16,512]
    const float* Q    = (const float*)d_in[2];  // [8192,256]
    const float* Wk   = (const float*)d_in[3];  // [256,1024]
    const float* Wv   = (const float*)d_in[4];  // [256,1024]
    const float* Wo   = (const float*)d_in[5];  // [8192,256]
    const float* bias = (const float*)d_in[6];  // [8192]
    float* out = (float*)d_out;                 // [16,8192]

    unsigned short* Xb   = (unsigned short*)d_ws;          // 8,388,608 elems
    unsigned short* Qb   = Xb + 8388608ull;                // 2,097,152
    unsigned short* Wob  = Qb + 2097152ull;                // 2,097,152
    unsigned short* Wkvb = Wob + 2097152ull;               // 524,288 (Wk 0-255, Wv 256-511)
    unsigned short* Kb   = Wkvb + 524288ull;               // 2,097,152
    unsigned short* Vb   = Kb + 2097152ull;                // 2,097,152  (total ~34.6 MB)

    cvt_all<<<dim3(3200), 256, 0, stream>>>(X, Q, Wo, Wk, Wv, Xb);
    kv_gemm<<<dim3(256), 256, 0, stream>>>(Xb, Wkvb, Kb, Vb);
    attn_fused<<<dim3(1024), 512, 0, stream>>>(Qb, Wob, Kb, Vb, mask, bias, out);
}

// Round 4
// 201.660 us; speedup vs baseline: 1.7035x; 1.1654x over previous
//
#include <hip/hip_runtime.h>
#include <hip/hip_bf16.h>

// Problem constants: B=16, T=512, H=1024, L=8192, D=256
// logits[b,l] = sum_t softmax_t(Q[l]·K[b,t]/16) * (Wout[l]·V[b,t]) + bias[l]

typedef __bf16 bf16x8 __attribute__((ext_vector_type(8)));
typedef float f32x4 __attribute__((ext_vector_type(4)));

__device__ __forceinline__ unsigned short f2bf(float f) {
    // round-to-nearest-even fp32 -> bf16 (finite inputs only)
    unsigned int u = __builtin_bit_cast(unsigned int, f);
    unsigned int lsb = (u >> 16) & 1u;
    u += 0x7fffu + lsb;
    return (unsigned short)(u >> 16);
}

// async global->LDS DMA: each lane contributes 16 B; LDS dest = wave-uniform
// base + lane*16 (m104/m108).
__device__ __forceinline__ void gld_lds16(const void* g, void* l) {
    __builtin_amdgcn_global_load_lds((__attribute__((address_space(1))) void*)g,
                                     (__attribute__((address_space(3))) void*)l,
                                     16, 0, 0);
}

// -----------------------------------------------------------------------------
// Fused fp32->bf16 conversion for all five tensors in one launch.
// Segments (float4 units): X 2097152 | Q 524288 | Wo 524288 | Wk 65536 | Wv 65536
// -----------------------------------------------------------------------------
__global__ __launch_bounds__(256) void cvt_all(const float* __restrict__ X,
                                               const float* __restrict__ Q,
                                               const float* __restrict__ Wo,
                                               const float* __restrict__ Wk,
                                               const float* __restrict__ Wv,
                                               unsigned short* __restrict__ dst) {
    int base = blockIdx.x * 1024 + threadIdx.x;
#pragma unroll
    for (int r = 0; r < 4; ++r) {
        int idx = base + r * 256;  // float4 index, < 3276800
        const float* src;
        int off;
        if (idx < 2097152)      { src = X;  off = idx; }
        else if (idx < 2621440) { src = Q;  off = idx - 2097152; }
        else if (idx < 3145728) { src = Wo; off = idx - 2621440; }
        else if (idx < 3211264) { src = Wk; off = idx - 3145728; }
        else                    { src = Wv; off = idx - 3211264; }
        float4 v = ((const float4*)src)[off];
        ushort4 o;
        o.x = f2bf(v.x); o.y = f2bf(v.y); o.z = f2bf(v.z); o.w = f2bf(v.w);
        ((ushort4*)dst)[idx] = o;
    }
}

// -----------------------------------------------------------------------------
// Phase 1: K,V projection. C[m][n] = sum_h X[m][h] * Wkv[n][h]
//   M = B*T = 8192, N = 512 (n<256 -> K dim d=n; else V dim d=n-256), K = 1024
// Tile: 128m x 128n per block (grid 64x4), 4 waves in 2x2, wave = 64m x 64n.
// (unchanged this round — isolating the attn changes)
// -----------------------------------------------------------------------------
__global__ __launch_bounds__(256) void kv_gemm(const unsigned short* __restrict__ Xb,
                                               const unsigned short* __restrict__ Wb,
                                               unsigned short* __restrict__ Kb,
                                               unsigned short* __restrict__ Vb) {
    __shared__ unsigned short Xs[128 * 72];  // 64-wide h-chunk, stride 72 (pad 8)
    __shared__ unsigned short Ws[128 * 72];
    const int bid = blockIdx.x;
    const int nt = bid & 3, mt = bid >> 2;
    const int m0 = mt * 128, n0 = nt * 128;
    const int tid = threadIdx.x;
    const int lane = tid & 63, w = tid >> 6;
    const int q = lane >> 4, ln = lane & 15;
    const int wm = (w & 1) * 64, wn = (w >> 1) * 64;

    f32x4 acc[4][4];
#pragma unroll
    for (int mi = 0; mi < 4; ++mi)
#pragma unroll
        for (int ni = 0; ni < 4; ++ni) acc[mi][ni] = f32x4{0.f, 0.f, 0.f, 0.f};

#pragma unroll 1
    for (int h0 = 0; h0 < 1024; h0 += 64) {
#pragma unroll
        for (int i = 0; i < 4; ++i) {  // stage X and Wkv tiles: 128 rows x 64 h each
            int c = tid + i * 256;
            int row = c >> 3, off = (c & 7) << 3;
            *(uint4*)(&Xs[row * 72 + off]) = *(const uint4*)(&Xb[(m0 + row) * 1024 + h0 + off]);
            *(uint4*)(&Ws[row * 72 + off]) = *(const uint4*)(&Wb[(n0 + row) * 1024 + h0 + off]);
        }
        __syncthreads();
#pragma unroll
        for (int ks = 0; ks < 64; ks += 32) {
            bf16x8 a[4], b[4];
#pragma unroll
            for (int mi = 0; mi < 4; ++mi)
                a[mi] = *(const bf16x8*)(&Xs[(wm + mi * 16 + ln) * 72 + ks + q * 8]);
#pragma unroll
            for (int ni = 0; ni < 4; ++ni)
                b[ni] = *(const bf16x8*)(&Ws[(wn + ni * 16 + ln) * 72 + ks + q * 8]);
#pragma unroll
            for (int mi = 0; mi < 4; ++mi)
#pragma unroll
                for (int ni = 0; ni < 4; ++ni)
                    acc[mi][ni] = __builtin_amdgcn_mfma_f32_16x16x32_bf16(
                        a[mi], b[ni], acc[mi][ni], 0, 0, 0);
        }
        __syncthreads();
    }
    // epilogue: C/D layout col(=n) = ln, row(=m) = q*4+reg
    {
        unsigned short* dst = (n0 < 256) ? Kb : Vb;  // uniform per block
        const int d0 = (n0 & 255) + wn;
#pragma unroll
        for (int mi = 0; mi < 4; ++mi)
#pragma unroll
            for (int ni = 0; ni < 4; ++ni) {
                int d = d0 + ni * 16 + ln;
#pragma unroll
                for (int r = 0; r < 4; ++r) {
                    int m = m0 + wm + mi * 16 + q * 4 + r;
                    dst[m * 256 + d] = f2bf(acc[mi][ni][r]);
                }
            }
    }
}

// -----------------------------------------------------------------------------
// Phase 2: fused S = Q·K^T, P = Wout·V^T, softmax-weighted reduce over t.
// Grid: 16 b x 64 l-tiles. Block = 256 threads = 4 waves, one 32-l strip each;
// every wave covers the full 32-t chunk (ni=0,1). 16 chunks of 32 t.
// LDS 66.5 KB -> 2 blocks/CU = two independent barrier domains that overlap.
// A-operands (Q,Wout, full d=256) in registers (compile-time indices only).
// K/V DMA-staged with a SWIZZLED source mapping: within each 1024-B group
// (2 t-rows), lane i carries (kk=i>>3, sub=(i>>2)&1, q=i&3), i.e. LDS chunk
// idx = 8*kk + q + 4*sub. Fragment reads then hit bank group
// (ln>>1)+4*(ln&1)+q mod 8 — a bijection over every 8-lane beat: conflict-free.
// -----------------------------------------------------------------------------
__global__ __launch_bounds__(256, 2) void attn_fused(const unsigned short* __restrict__ Qb,
                                                     const unsigned short* __restrict__ Wob,
                                                     const unsigned short* __restrict__ Kb,
                                                     const unsigned short* __restrict__ Vb,
                                                     const int* __restrict__ mask,
                                                     const float* __restrict__ bias,
                                                     float* __restrict__ out) {
    __shared__ unsigned short Ks[2][8320];  // 16 groups x 520 ushorts (1024 B + 16 B pad)
    __shared__ unsigned short Vs[2][8320];
    const int bid = blockIdx.x;
    const int bb = bid >> 6;             // batch
    const int l0 = (bid & 63) * 128;     // l-tile origin
    const int tid = threadIdx.x;
    const int lane = tid & 63, w = tid >> 6;   // w = l-strip 0..3
    const int q = lane >> 4, ln = lane & 15;
    // swizzled DMA per-lane source offset (ushorts): (kk, sub, q) from lane id
    const int laneoff = ((lane >> 3) * 32) + (((lane >> 2) & 1) * 256) + ((lane & 3) * 8);

    // Prologue: A-fragments for full d=256 (8 k-steps of 32) in registers.
    bf16x8 aQ[2][8], aW[2][8];
#pragma unroll
    for (int mi = 0; mi < 2; ++mi) {
        const int row = (l0 + w * 32 + mi * 16 + ln) * 256;
#pragma unroll
        for (int kk = 0; kk < 8; ++kk) {
            aQ[mi][kk] = *(const bf16x8*)(&Qb[row + kk * 32 + q * 8]);
            aW[mi][kk] = *(const bf16x8*)(&Wob[row + kk * 32 + q * 8]);
        }
    }

    float num[2][4], den[2][4];
#pragma unroll
    for (int mi = 0; mi < 2; ++mi)
#pragma unroll
        for (int r = 0; r < 4; ++r) { num[mi][r] = 0.f; den[mi][r] = 0.f; }

    // DMA-stage chunk c (32t x 256d of K and V) into parity c&1.
    // 32 groups (K: 0..15, V: 16..31); each of 4 waves issues 8.
    auto stage = [&](int c) {
        const int p = c & 1;
        const int rbase = bb * 512 + c * 32;
#pragma unroll
        for (int j = 0; j < 8; ++j) {
            int gid = w * 8 + j;        // wave-uniform, 0..31
            int g = gid & 15;
            const unsigned short* srcb = (gid < 16) ? Kb : Vb;
            unsigned short* dstb = (gid < 16) ? &Ks[p][0] : &Vs[p][0];
            gld_lds16(srcb + (((size_t)(rbase + 2 * g)) << 8) + laneoff,
                      dstb + g * 520);
        }
    };
    stage(0);

#pragma unroll 1
    for (int c = 0; c < 16; ++c) {
        __syncthreads();           // drains DMAs -> chunk c ready; parity c&1 free to reuse
        if (c < 15) stage(c + 1);  // prefetch lands during compute below
        const int p = c & 1;

        f32x4 Sa[2][2], Pa[2][2];
#pragma unroll
        for (int mi = 0; mi < 2; ++mi)
#pragma unroll
            for (int ni = 0; ni < 2; ++ni) {
                Sa[mi][ni] = f32x4{0.f, 0.f, 0.f, 0.f};
                Pa[mi][ni] = f32x4{0.f, 0.f, 0.f, 0.f};
            }

#pragma unroll
        for (int kk = 0; kk < 8; ++kk) {
            bf16x8 bK[2], bV[2];
#pragma unroll
            for (int ni = 0; ni < 2; ++ni) {
                int rr = ni * 16 + ln;  // t-row in chunk
                int off = (rr >> 1) * 520 + kk * 64 + (rr & 1) * 32 + q * 8;
                bK[ni] = *(const bf16x8*)(&Ks[p][off]);
                bV[ni] = *(const bf16x8*)(&Vs[p][off]);
            }
#pragma unroll
            for (int mi = 0; mi < 2; ++mi)
#pragma unroll
                for (int ni = 0; ni < 2; ++ni) {
                    Sa[mi][ni] = __builtin_amdgcn_mfma_f32_16x16x32_bf16(
                        aQ[mi][kk], bK[ni], Sa[mi][ni], 0, 0, 0);
                    Pa[mi][ni] = __builtin_amdgcn_mfma_f32_16x16x32_bf16(
                        aW[mi][kk], bV[ni], Pa[mi][ni], 0, 0, 0);
                }
        }
        // softmax partials. D layout: col(=t) = ln, row(=l) = q*4+r.
        // S ~N(0,0.02): exp without max-subtraction is exact softmax.
#pragma unroll
        for (int ni = 0; ni < 2; ++ni) {
            int t = c * 32 + ni * 16 + ln;
            bool ok = mask[bb * 512 + t] != 0;
#pragma unroll
            for (int mi = 0; mi < 2; ++mi)
#pragma unroll
                for (int r = 0; r < 4; ++r) {
                    float e = ok ? __expf(Sa[mi][ni][r] * 0.0625f) : 0.0f;
                    den[mi][r] += e;
                    num[mi][r] += e * Pa[mi][ni][r];
                }
        }
    }

    // reduce over the 16 t-columns (lanes ln) of each quad group; each wave
    // covered all 512 t, so no cross-wave reduction is needed.
#pragma unroll
    for (int mi = 0; mi < 2; ++mi)
#pragma unroll
        for (int r = 0; r < 4; ++r) {
            float n_ = num[mi][r], d_ = den[mi][r];
#pragma unroll
            for (int o = 1; o < 16; o <<= 1) {
                n_ += __shfl_xor(n_, o);
                d_ += __shfl_xor(d_, o);
            }
            if (ln == 0) {
                int l = l0 + w * 32 + mi * 16 + q * 4 + r;
                out[bb * 8192 + l] = n_ / d_ + bias[l];
            }
        }
}

extern "C" void kernel_launch(void* const* d_in, const int* in_sizes, int n_in,
                              void* d_out, int out_size, void* d_ws, size_t ws_size,
                              hipStream_t stream) {
    const float* X    = (const float*)d_in[0];  // [16,512,1024]
    const int*   mask = (const int*)d_in[1];    // [16,512]
    const float* Q    = (const float*)d_in[2];  // [8192,256]
    const float* Wk   = (const float*)d_in[3];  // [256,1024]
    const float* Wv   = (const float*)d_in[4];  // [256,1024]
    const float* Wo   = (const float*)d_in[5];  // [8192,256]
    const float* bias = (const float*)d_in[6];  // [8192]
    float* out = (float*)d_out;                 // [16,8192]

    unsigned short* Xb   = (unsigned short*)d_ws;          // 8,388,608 elems
    unsigned short* Qb   = Xb + 8388608ull;                // 2,097,152
    unsigned short* Wob  = Qb + 2097152ull;                // 2,097,152
    unsigned short* Wkvb = Wob + 2097152ull;               // 524,288 (Wk 0-255, Wv 256-511)
    unsigned short* Kb   = Wkvb + 524288ull;               // 2,097,152
    unsigned short* Vb   = Kb + 2097152ull;                // 2,097,152  (total ~34.6 MB)

    cvt_all<<<dim3(3200), 256, 0, stream>>>(X, Q, Wo, Wk, Wv, Xb);
    kv_gemm<<<dim3(256), 256, 0, stream>>>(Xb, Wkvb, Kb, Vb);
    attn_fused<<<dim3(1024), 256, 0, stream>>>(Qb, Wob, Kb, Vb, mask, bias, out);
}